// Round 6
// baseline (210.726 us; speedup 1.0000x reference)
//
#include <hip/hip_runtime.h>

// out[p] = max(0, segment_max over rows n with idx[n]==p of (feats[n].W + b))
//
// feats: [N][32] fp32, W: [1][32] fp32, b: [1] fp32, idx: [N] int32, out: [P] fp32.
//
// Memory-bound streaming. Each wave-iteration handles a 64-row super-group
// (8 KiB contiguous): 8 independent float4 loads per lane (MLP=8), 8-lane
// shuffle-tree per row-dot, full-lane epilogue (lane l owns row
// (l>>3)+8*(l&7), selected via cndmask tree).
//
// Atomic-traffic reduction (this round's change): device-scope atomics
// execute at the shared LLC (per-XCD L2s are non-coherent), so each atomic
// burns a fabric request slot. Filter with a plain cached load first:
//   cur = out_i[i];  if (bits(r) > cur) atomicMax(...)
// cur >= 0 always, so the int compare also subsumes the r>0 check (negative
// float bits are negative ints). Stale L2 copies are <= the LLC value ->
// the filter only errs toward extra (harmless) atomics. feats loads are now
// NON-temporal-free: the 512MB stream churns L2 every ~7us, which evicts
// out[] lines and keeps the filter fresh.

typedef float f32x4 __attribute__((ext_vector_type(4)));

__global__ __launch_bounds__(256, 4) void miniNN_seglinmax_kernel(
    const f32x4* __restrict__ feats4,    // N*8 float4
    const float* __restrict__ W,         // 32 floats
    const float* __restrict__ b,         // 1 float
    const int*   __restrict__ idx,       // N int32
    int*         __restrict__ out_i,     // P floats viewed as int (pre-zeroed)
    int          n_rows)
{
    const int l    = threadIdx.x & 63;
    const int gwid = blockIdx.x * (blockDim.x >> 6) + (threadIdx.x >> 6);
    const int nw   = gridDim.x * (blockDim.x >> 6);

    const f32x4 wv  = ((const f32x4*)W)[l & 7];
    const float bias = b[0];

    // lane l owns row (l>>3) + 8*(l&7) within each 64-row super-group
    const int myrow = (l >> 3) + ((l & 7) << 3);

    const int nsuper = n_rows >> 6;      // 64 rows per super-group
    for (int sg = gwid; sg < nsuper; sg += nw) {
        // Issue the scattered filter chain early so it overlaps the dots.
        const int i   = idx[(sg << 6) + myrow];
        const int cur = out_i[i];        // plain cached load: filter threshold

        // 8 KiB contiguous per wave-iteration; 8 loads in flight per lane.
        const f32x4* p = feats4 + (sg << 9) + l;
        const f32x4 v0 = p[0];
        const f32x4 v1 = p[64];
        const f32x4 v2 = p[128];
        const f32x4 v3 = p[192];
        const f32x4 v4 = p[256];
        const f32x4 v5 = p[320];
        const f32x4 v6 = p[384];
        const f32x4 v7 = p[448];

        float s[8];
        s[0] = v0.x * wv.x + v0.y * wv.y + v0.z * wv.z + v0.w * wv.w;
        s[1] = v1.x * wv.x + v1.y * wv.y + v1.z * wv.z + v1.w * wv.w;
        s[2] = v2.x * wv.x + v2.y * wv.y + v2.z * wv.z + v2.w * wv.w;
        s[3] = v3.x * wv.x + v3.y * wv.y + v3.z * wv.z + v3.w * wv.w;
        s[4] = v4.x * wv.x + v4.y * wv.y + v4.z * wv.z + v4.w * wv.w;
        s[5] = v5.x * wv.x + v5.y * wv.y + v5.z * wv.z + v5.w * wv.w;
        s[6] = v6.x * wv.x + v6.y * wv.y + v6.z * wv.z + v6.w * wv.w;
        s[7] = v7.x * wv.x + v7.y * wv.y + v7.z * wv.z + v7.w * wv.w;

        #pragma unroll
        for (int k = 0; k < 8; ++k) {
            s[k] += __shfl_xor(s[k], 1);
            s[k] += __shfl_xor(s[k], 2);
            s[k] += __shfl_xor(s[k], 4);
        }

        // lane l picks dot k = l&7 (all lanes of a group hold identical s[k])
        const bool b0 = (l & 1) != 0;
        const bool b1 = (l & 2) != 0;
        const bool b2 = (l & 4) != 0;
        const float t0 = b0 ? s[1] : s[0];
        const float t1 = b0 ? s[3] : s[2];
        const float t2 = b0 ? s[5] : s[4];
        const float t3 = b0 ? s[7] : s[6];
        const float u0 = b1 ? t1 : t0;
        const float u1 = b1 ? t3 : t2;
        const float dot = b2 ? u1 : u0;

        const float r  = dot + bias;
        const int   rb = __float_as_int(r);
        // cur >= 0, so rb > cur implies r > 0; rb <= 0 (incl. negative-float
        // bits) never passes. Stale cur only causes extra atomics, never
        // missed ones — atomicMax remains the authoritative RMW.
        if (rb > cur) atomicMax(out_i + i, rb);
    }

    // Tail rows (n_rows % 64 != 0) — scalar path, negligible work.
    const int tail_start = nsuper << 6;
    const int gtid = blockIdx.x * blockDim.x + threadIdx.x;
    const int row  = tail_start + gtid;
    if (row < n_rows) {
        const float* f = (const float*)feats4 + (long long)row * 32;
        float r = bias;
        #pragma unroll
        for (int k = 0; k < 32; ++k) r += f[k] * W[k];
        const int rb = __float_as_int(r);
        const int i  = idx[row];
        if (rb > out_i[i]) atomicMax(out_i + i, rb);
    }
}

extern "C" void kernel_launch(void* const* d_in, const int* in_sizes, int n_in,
                              void* d_out, int out_size, void* d_ws, size_t ws_size,
                              hipStream_t stream) {
    const float* feats = (const float*)d_in[0];
    const float* W     = (const float*)d_in[1];
    const float* b     = (const float*)d_in[2];
    const int*   idx   = (const int*)d_in[3];
    const int n_rows   = in_sizes[0] / 32;

    // Zero output: handles empty segments (segment_max -> -inf, then
    // max(.,0) = 0) and is the identity for the positive-float atomicMax.
    (void)hipMemsetAsync(d_out, 0, (size_t)out_size * sizeof(float), stream);

    // Balanced grid: waves = blocks*4; minimize total wave-iteration slots
    // (waves * iters) over the 64-row super-groups. For nsuper=62500 picks
    // 1954 blocks: 7816 waves x 8 iters = 62528 (99.96% utilization).
    const int nsuper = n_rows >> 6;
    int best_blocks = 2048;
    long long best_cost = 0x7fffffffffffffffLL;
    for (int blk = 256; blk <= 2048; ++blk) {
        const long long waves = (long long)blk * 4;
        const long long iters = (nsuper + waves - 1) / waves;
        const long long cost  = waves * iters;
        if (cost < best_cost || (cost == best_cost && blk > best_blocks)) {
            best_cost = cost; best_blocks = blk;
        }
    }

    miniNN_seglinmax_kernel<<<best_blocks, 256, 0, stream>>>(
        (const f32x4*)feats, W, b, idx, (int*)d_out, n_rows);
}

// Round 7
// 115.264 us; speedup vs baseline: 1.8282x; 1.8282x over previous
//
#include <hip/hip_runtime.h>

// out[p] = max(0, segment_max over rows n with idx[n]==p of (feats[n].W + b))
//
// feats: [N][32] fp32, W: [1][32] fp32, b: [1] fp32, idx: [N] int32, out: [P] fp32.
//
// Memory-bound streaming, measured-best structure (R4, 114.5 us = 4.61 TB/s):
// each wave-iteration handles a 32-row super-group (4 KiB contiguous),
// 4 independent nontemporal float4 loads per lane (MLP=4 per unroll step,
// 8 KiB total with the 2x row blocks), 8-lane shuffle tree per row-dot.
// Segment max via FIRE-AND-FORGET integer atomicMax on positive-float bit
// patterns (out pre-zeroed; r <= 0 never beats the 0 floor). Do NOT filter
// atomics with a plain read of out[]: the feats stream churns L2, so the
// filter read misses to LLC on the critical path — measured 210 us vs 114.

typedef float f32x4 __attribute__((ext_vector_type(4)));

__global__ __launch_bounds__(256, 4) void miniNN_seglinmax_kernel(
    const f32x4* __restrict__ feats4,    // N*8 float4
    const float* __restrict__ W,         // 32 floats
    const float* __restrict__ b,         // 1 float
    const int*   __restrict__ idx,       // N int32
    int*         __restrict__ out_i,     // P floats viewed as int (pre-zeroed)
    int          n_rows)
{
    const int lane = threadIdx.x & 63;
    const int sub  = lane & 7;           // which float4 within a row
    const int j    = lane >> 3;          // which row within an 8-row group
    const int gwid = blockIdx.x * (blockDim.x >> 6) + (threadIdx.x >> 6);
    const int nw   = gridDim.x * (blockDim.x >> 6);

    const f32x4 wv  = ((const f32x4*)W)[sub];
    const float bias = b[0];

    const int nsuper = n_rows >> 5;      // 32 rows per super-group
    for (int sg = gwid; sg < nsuper; sg += nw) {
        // 4 KiB contiguous per wave-iteration; 4 loads in flight per lane.
        // Nontemporal: feats is streamed exactly once — keep out/W in cache.
        const f32x4* p = feats4 + (sg << 8) + lane;
        const f32x4 v0 = __builtin_nontemporal_load(p);
        const f32x4 v1 = __builtin_nontemporal_load(p + 64);
        const f32x4 v2 = __builtin_nontemporal_load(p + 128);
        const f32x4 v3 = __builtin_nontemporal_load(p + 192);

        float s0 = v0.x * wv.x + v0.y * wv.y + v0.z * wv.z + v0.w * wv.w;
        float s1 = v1.x * wv.x + v1.y * wv.y + v1.z * wv.z + v1.w * wv.w;
        float s2 = v2.x * wv.x + v2.y * wv.y + v2.z * wv.z + v2.w * wv.w;
        float s3 = v3.x * wv.x + v3.y * wv.y + v3.z * wv.z + v3.w * wv.w;

        s0 += __shfl_xor(s0, 1); s0 += __shfl_xor(s0, 2); s0 += __shfl_xor(s0, 4);
        s1 += __shfl_xor(s1, 1); s1 += __shfl_xor(s1, 2); s1 += __shfl_xor(s1, 4);
        s2 += __shfl_xor(s2, 1); s2 += __shfl_xor(s2, 2); s2 += __shfl_xor(s2, 4);
        s3 += __shfl_xor(s3, 1); s3 += __shfl_xor(s3, 2); s3 += __shfl_xor(s3, 4);

        if (sub == 0) {
            const int rowbase = (sg << 5) + j;
            const int i0 = __builtin_nontemporal_load(idx + rowbase);
            const int i1 = __builtin_nontemporal_load(idx + rowbase + 8);
            const int i2 = __builtin_nontemporal_load(idx + rowbase + 16);
            const int i3 = __builtin_nontemporal_load(idx + rowbase + 24);
            const float r0 = s0 + bias;
            const float r1 = s1 + bias;
            const float r2 = s2 + bias;
            const float r3 = s3 + bias;
            if (r0 > 0.0f) atomicMax(out_i + i0, __float_as_int(r0));
            if (r1 > 0.0f) atomicMax(out_i + i1, __float_as_int(r1));
            if (r2 > 0.0f) atomicMax(out_i + i2, __float_as_int(r2));
            if (r3 > 0.0f) atomicMax(out_i + i3, __float_as_int(r3));
        }
    }

    // Tail rows (n_rows % 32 != 0) — scalar path, negligible work.
    const int tail_start = nsuper << 5;
    const int gtid = blockIdx.x * blockDim.x + threadIdx.x;
    const int row  = tail_start + gtid;
    if (row < n_rows) {
        const float* f = (const float*)feats4 + (long long)row * 32;
        float r = bias;
        #pragma unroll
        for (int k = 0; k < 32; ++k) r += f[k] * W[k];
        if (r > 0.0f) atomicMax(out_i + idx[row], __float_as_int(r));
    }
}

extern "C" void kernel_launch(void* const* d_in, const int* in_sizes, int n_in,
                              void* d_out, int out_size, void* d_ws, size_t ws_size,
                              hipStream_t stream) {
    const float* feats = (const float*)d_in[0];
    const float* W     = (const float*)d_in[1];
    const float* b     = (const float*)d_in[2];
    const int*   idx   = (const int*)d_in[3];
    const int n_rows   = in_sizes[0] / 32;

    // Zero output: handles empty segments (segment_max -> -inf, then
    // max(.,0) = 0) and is the identity for the positive-float atomicMax.
    (void)hipMemsetAsync(d_out, 0, (size_t)out_size * sizeof(float), stream);

    // Balanced grid: waves = blocks*4; minimize total wave-iteration slots
    // (waves * iters) over the 32-row super-groups. For nsuper=125000 picks
    // 1954 blocks: 7816 waves x 16 iters = 125056 (99.96% utilization).
    const int nsuper = n_rows >> 5;
    int best_blocks = 2048;
    long long best_cost = 0x7fffffffffffffffLL;
    for (int blk = 256; blk <= 2048; ++blk) {
        const long long waves = (long long)blk * 4;
        const long long iters = (nsuper + waves - 1) / waves;
        const long long cost  = waves * iters;
        if (cost < best_cost || (cost == best_cost && blk > best_blocks)) {
            best_cost = cost; best_blocks = blk;
        }
    }

    miniNN_seglinmax_kernel<<<best_blocks, 256, 0, stream>>>(
        (const f32x4*)feats, W, b, idx, (int*)d_out, n_rows);
}